// Round 4
// baseline (1805.004 us; speedup 1.0000x reference)
//
#include <hip/hip_runtime.h>

// Problem constants
#define BATCH 32
#define HIN 224
#define WIN 224
#define KCH 64
#define KS 7
#define OH 218
#define OW 218

// Tiling: 256 threads = 4 waves; each wave owns 8 consecutive output rows x full width.
// Block: 32 rows x 218 cols x 8 channels. 7 bands cover 218 rows (rows >=218 masked).
// Row parity is compile-time: h0 = band*32 (even), r0 = wave*8 (even) -> orow parity = i&1.
//   even i: lane L stores cols 4L..4L+3   (row byte off ≡ 0 mod 16 -> aligned float4)
//   odd  i: lane L stores cols 4L-2..4L+1 (row byte off ≡ 8 mod 16; (4L-2)*4 ≡ 8 -> aligned float4)
// All output stores are DENSE (no intra-instruction holes) + nontemporal (no L2/L3 RFO/alloc).
#define TILE_H 32
#define IN_TILE_H 38      // TILE_H + 6
#define LDS_STRIDE 240    // 4 leading zero-pad floats + 236 staged cols (16B-aligned rows)
#define CH_PER_BLOCK 8
#define NBANDS 7          // 7*32 = 224 >= 218

typedef float f32x4 __attribute__((ext_vector_type(4)));
typedef float f32x2 __attribute__((ext_vector_type(2)));

__device__ __forceinline__ void nt_store4(float* p, float a, float b, float c, float d) {
    f32x4 v; v.x = a; v.y = b; v.z = c; v.w = d;
    __builtin_nontemporal_store(v, reinterpret_cast<f32x4*>(p));
}
__device__ __forceinline__ void nt_store2(float* p, float a, float b) {
    f32x2 v; v.x = a; v.y = b;
    __builtin_nontemporal_store(v, reinterpret_cast<f32x2*>(p));
}

__global__ __launch_bounds__(256, 4)
void conv7x7_kernel(const float* __restrict__ x,
                    const float* __restrict__ kern,
                    float* __restrict__ out) {
    __shared__ float tile[IN_TILE_H][LDS_STRIDE];

    const int band = blockIdx.x;          // 0..6  (H bands of 32 rows)
    const int kg   = blockIdx.y;          // 0..7  (channel groups)
    const int b    = blockIdx.z;          // 0..31

    const int h0 = band * TILE_H;

    const int tid  = threadIdx.x;         // 0..255
    const int wv   = tid >> 6;            // wave 0..3
    const int lane = tid & 63;

    // ---- zero the 4-float leading pad (read by odd-row left-edge lanes) ----
    if (tid < IN_TILE_H) {
        f32x4 z; z.x = 0.f; z.y = 0.f; z.z = 0.f; z.w = 0.f;
        *reinterpret_cast<f32x4*>(&tile[tid][0]) = z;
    }

    // ---- stage input band: rows h0..h0+37, cols 0..235 at tile[r][4+col] ----
    const float* xb = x + b * (HIN * WIN);
    const int NV = (LDS_STRIDE - 4) / 4;  // 59 float4 per row
    for (int idx = tid; idx < IN_TILE_H * NV; idx += 256) {
        const int r  = idx / NV;
        const int cg = idx - r * NV;
        const int sr = h0 + r;
        const int sc = cg * 4;
        float4 v;
        if (sr < HIN && sc + 3 < WIN) {
            v = *reinterpret_cast<const float4*>(xb + sr * WIN + sc);
        } else {
            float t0 = (sr < HIN && sc + 0 < WIN) ? xb[sr * WIN + sc + 0] : 0.f;
            float t1 = (sr < HIN && sc + 1 < WIN) ? xb[sr * WIN + sc + 1] : 0.f;
            float t2 = (sr < HIN && sc + 2 < WIN) ? xb[sr * WIN + sc + 2] : 0.f;
            float t3 = (sr < HIN && sc + 3 < WIN) ? xb[sr * WIN + sc + 3] : 0.f;
            v = make_float4(t0, t1, t2, t3);
        }
        *reinterpret_cast<float4*>(&tile[r][4 + sc]) = v;
    }
    __syncthreads();

    const int r0 = wv * 8;                          // first out-row within band (even)
    const int cl = (lane < 54) ? lane : 54;         // clamp idle lanes (broadcast reads)
    const int c0 = cl * 4;                          // even-row first out-col

    #pragma unroll 1
    for (int kk = 0; kk < CH_PER_BLOCK; ++kk) {
        const int k = kg * CH_PER_BLOCK + kk;
        const float* __restrict__ wk = kern + k * (KS * KS);  // wave-uniform -> s_load

        float acc[8][4];
        #pragma unroll
        for (int i = 0; i < 8; ++i)
            #pragma unroll
            for (int j = 0; j < 4; ++j)
                acc[i][j] = 0.f;

        #pragma unroll
        for (int ii = 0; ii < 14; ++ii) {
            // xr covers input cols (c0-4 .. c0+11); float index in tile = c0 + 0..15
            float xr[16];
            *reinterpret_cast<float4*>(&xr[0]) =
                *reinterpret_cast<const float4*>(&tile[r0 + ii][c0]);
            *reinterpret_cast<float4*>(&xr[4]) =
                *reinterpret_cast<const float4*>(&tile[r0 + ii][c0 + 4]);
            *reinterpret_cast<float4*>(&xr[8]) =
                *reinterpret_cast<const float4*>(&tile[r0 + ii][c0 + 8]);
            *reinterpret_cast<float4*>(&xr[12]) =
                *reinterpret_cast<const float4*>(&tile[r0 + ii][c0 + 12]);

            #pragma unroll
            for (int i = 0; i < 8; ++i) {
                const int ki = ii - i;
                if (ki >= 0 && ki < 7) {
                    const int ofs = (i & 1) ? 2 : 4;   // compile-time per i
                    #pragma unroll
                    for (int kj = 0; kj < 7; ++kj) {
                        const float wv2 = wk[ki * 7 + kj];
                        #pragma unroll
                        for (int j = 0; j < 4; ++j)
                            acc[i][j] = fmaf(wv2, xr[ofs + kj + j], acc[i][j]);
                    }
                }
            }
        }

        // ---- store: every instruction dense + 16B-aligned, nontemporal ----
        float* ob = out + (size_t)(b * KCH + k) * (OH * OW);
        #pragma unroll
        for (int i = 0; i < 8; ++i) {
            const int orow = h0 + r0 + i;
            if (orow < OH) {
                float* rowp = ob + orow * OW;
                if ((i & 1) == 0) {
                    // even row: lanes 0..53 cover cols 0..215; lane 54 tail cols 216,217
                    if (lane < 54) {
                        nt_store4(rowp + c0, acc[i][0], acc[i][1], acc[i][2], acc[i][3]);
                    } else if (lane == 54) {
                        nt_store2(rowp + 216, acc[i][0], acc[i][1]);
                    }
                } else {
                    // odd row: lane L computed cols 4L-2..4L+1; lanes 1..54 cover 2..217;
                    // lane 0 head cols 0,1 (its acc[2],acc[3])
                    if (lane == 0) {
                        nt_store2(rowp, acc[i][2], acc[i][3]);
                    } else if (lane <= 54) {
                        nt_store4(rowp + c0 - 2, acc[i][0], acc[i][1], acc[i][2], acc[i][3]);
                    }
                }
            }
        }
    }
}

extern "C" void kernel_launch(void* const* d_in, const int* in_sizes, int n_in,
                              void* d_out, int out_size, void* d_ws, size_t ws_size,
                              hipStream_t stream) {
    const float* x    = (const float*)d_in[0];   // (32,224,224) f32
    const float* kern = (const float*)d_in[1];   // (64,7,7) f32
    float* out        = (float*)d_out;           // (32,64,218,218) f32

    dim3 grid(NBANDS, KCH / CH_PER_BLOCK, BATCH); // 7 x 8 x 32 = 1792 blocks
    dim3 block(256, 1, 1);
    conv7x7_kernel<<<grid, block, 0, stream>>>(x, kern, out);
}